// Round 1
// baseline (514.435 us; speedup 1.0000x reference)
//
#include <hip/hip_runtime.h>

#define H 2048
#define HH (H * H)
#define NIDX 2097152
#define BINS 256
#define CH 3

// ws layout
// 0     : uint hist_dst[3][256]   (3072 B)
// 3072  : uint hist_ref[3][256]   (3072 B)
// 6144  : int  table[3][256]      (3072 B)
// 9216  : double acc              (8 B)
// 16384 : uchar selected[H*H]     (4 MiB)
#define WS_HIST_DST 0
#define WS_HIST_REF 3072
#define WS_TABLE    6144
#define WS_ACC      9216
#define WS_SEL      16384

__device__ __forceinline__ int bin_of(float v) {
    int b = (int)floorf(v);
    return min(max(b, 0), BINS - 1);
}

__global__ __launch_bounds__(256) void hist_kernel(
    const int* __restrict__ idx0, const int* __restrict__ idx1,
    const int* __restrict__ idx2, const int* __restrict__ idx3,
    const float* __restrict__ mask_src, const float* __restrict__ mask_tar,
    const float* __restrict__ refimg, const float* __restrict__ tgtimg,
    unsigned int* __restrict__ hist_dst, unsigned int* __restrict__ hist_ref,
    unsigned char* __restrict__ selected)
{
    __shared__ unsigned int hd[CH * BINS];
    __shared__ unsigned int hr[CH * BINS];
    for (int i = threadIdx.x; i < CH * BINS; i += 256) { hd[i] = 0u; hr[i] = 0u; }
    __syncthreads();

    const int lane = threadIdx.x & 63;
    const int stride = gridDim.x * 256;
    for (int k = blockIdx.x * 256 + threadIdx.x; k < NIDX; k += stride) {
        // ---- dst side: ref_masked gathered at (idx0, idx1) ----
        {
            int y = idx0[k], x = idx1[k];
            int p = y * H + x;
            float m = mask_src[p];
            selected[p] = 1;
            bool z = (m == 0.0f);
            if (!z) {
                #pragma unroll
                for (int c = 0; c < CH; ++c) {
                    float v = (refimg[c * HH + p] * 0.5f + 0.5f) * 255.0f * m;
                    atomicAdd(&hd[c * BINS + bin_of(v)], 1u);
                }
            }
            unsigned long long zm = __ballot(z);
            if (lane == 0) {
                unsigned int cnt = (unsigned int)__popcll(zm);
                if (cnt) {
                    atomicAdd(&hd[0 * BINS], cnt);
                    atomicAdd(&hd[1 * BINS], cnt);
                    atomicAdd(&hd[2 * BINS], cnt);
                }
            }
        }
        // ---- ref side: target_masked gathered at (idx2, idx3) ----
        {
            int y = idx2[k], x = idx3[k];
            int p = y * H + x;
            float m = mask_tar[p];
            bool z = (m == 0.0f);
            if (!z) {
                #pragma unroll
                for (int c = 0; c < CH; ++c) {
                    float v = (tgtimg[c * HH + p] * 0.5f + 0.5f) * 255.0f * m;
                    atomicAdd(&hr[c * BINS + bin_of(v)], 1u);
                }
            }
            unsigned long long zm = __ballot(z);
            if (lane == 0) {
                unsigned int cnt = (unsigned int)__popcll(zm);
                if (cnt) {
                    atomicAdd(&hr[0 * BINS], cnt);
                    atomicAdd(&hr[1 * BINS], cnt);
                    atomicAdd(&hr[2 * BINS], cnt);
                }
            }
        }
    }

    __syncthreads();
    for (int i = threadIdx.x; i < CH * BINS; i += 256) {
        unsigned int v = hd[i];
        if (v) atomicAdd(&hist_dst[i], v);
        v = hr[i];
        if (v) atomicAdd(&hist_ref[i], v);
    }
}

__global__ __launch_bounds__(256) void table_kernel(
    const unsigned int* __restrict__ hist_dst,
    const unsigned int* __restrict__ hist_ref,
    int* __restrict__ table)
{
    __shared__ float cd[CH * BINS];
    __shared__ float cr[CH * BINS];
    if (threadIdx.x < 6) {
        int c = threadIdx.x % 3;
        const unsigned int* h = (threadIdx.x < 3) ? hist_dst : hist_ref;
        float* out = (threadIdx.x < 3) ? cd : cr;
        float run = 0.0f;
        for (int i = 0; i < BINS; ++i) {
            run += (float)h[c * BINS + i];
            out[c * BINS + i] = run;
        }
        float tot = run;  // == N exactly (integers < 2^24 in f32)
        for (int i = 0; i < BINS; ++i) out[c * BINS + i] /= tot;
    }
    __syncthreads();

    int i = threadIdx.x;  // 0..255
    for (int c = 0; c < CH; ++c) {
        int t;
        if (i == 0) t = 0;
        else if (i == BINS - 1) t = BINS - 1;
        else {
            float r = cd[c * BINS + i];
            t = i;  // not-found default
            for (int j = 0; j < BINS - 1; ++j) {
                float lo = cr[c * BINS + j];
                float hi = cr[c * BINS + j + 1];
                if (lo <= r && r <= hi) { t = j + 1; break; }
            }
        }
        table[c * BINS + i] = t;
    }
}

__global__ __launch_bounds__(256) void loss_kernel(
    const float* __restrict__ input, const float* __restrict__ refimg,
    const float* __restrict__ mask_src, const unsigned char* __restrict__ selected,
    const int* __restrict__ table, double* __restrict__ acc)
{
    __shared__ int tab[CH * BINS];
    for (int i = threadIdx.x; i < CH * BINS; i += 256) tab[i] = table[i];
    __syncthreads();

    float lsum = 0.0f;
    const int nquads = HH / 4;
    const int stride = gridDim.x * 256;
    for (int q = blockIdx.x * 256 + threadIdx.x; q < nquads; q += stride) {
        float4 m4 = ((const float4*)mask_src)[q];
        uchar4 s4 = ((const uchar4*)selected)[q];
        const float mm[4] = { m4.x, m4.y, m4.z, m4.w };
        const unsigned char ss[4] = { s4.x, s4.y, s4.z, s4.w };
        #pragma unroll
        for (int c = 0; c < CH; ++c) {
            float4 a4 = ((const float4*)(input + (size_t)c * HH))[q];
            float4 r4 = ((const float4*)(refimg + (size_t)c * HH))[q];
            const float aa[4] = { a4.x, a4.y, a4.z, a4.w };
            const float rr[4] = { r4.x, r4.y, r4.z, r4.w };
            #pragma unroll
            for (int e = 0; e < 4; ++e) {
                float m = mm[e];
                float av = (aa[e] * 0.5f + 0.5f) * 255.0f * m;
                float rv = (rr[e] * 0.5f + 0.5f) * 255.0f * m;
                float mv;
                if (ss[e]) {
                    mv = m * (float)tab[c * BINS + bin_of(rv)];
                } else {
                    mv = m * rv;  // m in {0,1} -> == rv
                }
                lsum += fabsf(av - mv);
            }
        }
    }

    // block reduction in double
    double d = (double)lsum;
    #pragma unroll
    for (int off = 32; off; off >>= 1) d += __shfl_down(d, off);
    __shared__ double wsum[4];
    int wid = threadIdx.x >> 6;
    int lane = threadIdx.x & 63;
    if (lane == 0) wsum[wid] = d;
    __syncthreads();
    if (threadIdx.x == 0) {
        double t = wsum[0] + wsum[1] + wsum[2] + wsum[3];
        atomicAdd(acc, t);
    }
}

__global__ void finalize_kernel(const double* __restrict__ acc, float* __restrict__ out)
{
    if (threadIdx.x == 0 && blockIdx.x == 0) {
        out[0] = (float)(acc[0] / (double)(CH * (double)HH));
    }
}

extern "C" void kernel_launch(void* const* d_in, const int* in_sizes, int n_in,
                              void* d_out, int out_size, void* d_ws, size_t ws_size,
                              hipStream_t stream)
{
    const float* input    = (const float*)d_in[0];
    const float* target   = (const float*)d_in[1];
    const float* mask_src = (const float*)d_in[2];
    const float* mask_tar = (const float*)d_in[3];
    const int*   idx0     = (const int*)d_in[4];
    const int*   idx1     = (const int*)d_in[5];
    const int*   idx2     = (const int*)d_in[6];
    const int*   idx3     = (const int*)d_in[7];
    const float* refimg   = (const float*)d_in[8];

    char* ws = (char*)d_ws;
    unsigned int* hist_dst = (unsigned int*)(ws + WS_HIST_DST);
    unsigned int* hist_ref = (unsigned int*)(ws + WS_HIST_REF);
    int*          table    = (int*)(ws + WS_TABLE);
    double*       acc      = (double*)(ws + WS_ACC);
    unsigned char* selected = (unsigned char*)(ws + WS_SEL);

    hipMemsetAsync(d_ws, 0, (size_t)WS_SEL + (size_t)HH, stream);

    hist_kernel<<<1024, 256, 0, stream>>>(idx0, idx1, idx2, idx3,
                                          mask_src, mask_tar, refimg, target,
                                          hist_dst, hist_ref, selected);
    table_kernel<<<1, 256, 0, stream>>>(hist_dst, hist_ref, table);
    loss_kernel<<<2048, 256, 0, stream>>>(input, refimg, mask_src, selected, table, acc);
    finalize_kernel<<<1, 64, 0, stream>>>(acc, (float*)d_out);
}

// Round 2
// 512.763 us; speedup vs baseline: 1.0033x; 1.0033x over previous
//
#include <hip/hip_runtime.h>

#define H 2048
#define HH (H * H)
#define NIDX 2097152
#define BINS 256
#define CH 3

// ws layout
// 0      : uint hist_dst[3][256]            (3072 B)
// 3072   : uint hist_ref[3][256]            (3072 B)
// 6144   : int  table[3][256]               (3072 B)
// 9216   : double acc                       (8 B)
// 16384  : uint cnt_dst[HH/2]  (2x16-bit packed counts, 8.4 MB)
// +HH*2  : uint cnt_ref[HH/2]  (8.4 MB)
#define WS_HIST_DST 0
#define WS_HIST_REF 3072
#define WS_TABLE    6144
#define WS_ACC      9216
#define WS_CNT_DST  16384
#define WS_CNT_REF  (16384 + (size_t)HH * 2)
#define WS_ZERO_BYTES (16384 + (size_t)HH * 4)

__device__ __forceinline__ int bin_of(float v) {
    int b = (int)floorf(v);
    return min(max(b, 0), BINS - 1);
}

// 16-bit packed counter increment: pixel p lives in word p>>1, half p&1.
// Max per-pixel multiplicity ~O(10) for random idx, far below 65536.
__device__ __forceinline__ void cnt_inc(unsigned int* cnt, int p) {
    atomicAdd(&cnt[p >> 1], (p & 1) ? 0x10000u : 1u);
}

__global__ __launch_bounds__(256) void scatter_kernel(
    const int4* __restrict__ idx0, const int4* __restrict__ idx1,
    const int4* __restrict__ idx2, const int4* __restrict__ idx3,
    unsigned int* __restrict__ cnt_dst, unsigned int* __restrict__ cnt_ref)
{
    const int n4 = NIDX / 4;
    const int stride = gridDim.x * 256;
    for (int k = blockIdx.x * 256 + threadIdx.x; k < n4; k += stride) {
        int4 a = idx0[k], b = idx1[k], c = idx2[k], d = idx3[k];
        cnt_inc(cnt_dst, a.x * H + b.x);
        cnt_inc(cnt_dst, a.y * H + b.y);
        cnt_inc(cnt_dst, a.z * H + b.z);
        cnt_inc(cnt_dst, a.w * H + b.w);
        cnt_inc(cnt_ref, c.x * H + d.x);
        cnt_inc(cnt_ref, c.y * H + d.y);
        cnt_inc(cnt_ref, c.z * H + d.z);
        cnt_inc(cnt_ref, c.w * H + d.w);
    }
}

__global__ __launch_bounds__(256) void sweep_kernel(
    const float* __restrict__ mask_src, const float* __restrict__ mask_tar,
    const float* __restrict__ refimg, const float* __restrict__ tgtimg,
    const unsigned int* __restrict__ cnt_dst, const unsigned int* __restrict__ cnt_ref,
    unsigned int* __restrict__ hist_dst, unsigned int* __restrict__ hist_ref)
{
    __shared__ unsigned int hd[CH * BINS];
    __shared__ unsigned int hr[CH * BINS];
    for (int i = threadIdx.x; i < CH * BINS; i += 256) { hd[i] = 0u; hr[i] = 0u; }
    __syncthreads();

    const int nq = HH / 4;
    const int stride = gridDim.x * 256;
    for (int q = blockIdx.x * 256 + threadIdx.x; q < nq; q += stride) {
        uint2 wd = ((const uint2*)cnt_dst)[q];
        uint2 wr = ((const uint2*)cnt_ref)[q];
        unsigned int cd[4] = { wd.x & 0xFFFFu, wd.x >> 16, wd.y & 0xFFFFu, wd.y >> 16 };
        unsigned int cr[4] = { wr.x & 0xFFFFu, wr.x >> 16, wr.y & 0xFFFFu, wr.y >> 16 };
        float4 ms4 = ((const float4*)mask_src)[q];
        float4 mt4 = ((const float4*)mask_tar)[q];
        const float ms[4] = { ms4.x, ms4.y, ms4.z, ms4.w };
        const float mt[4] = { mt4.x, mt4.y, mt4.z, mt4.w };

        float rv[CH][4], tv[CH][4];
        #pragma unroll
        for (int c = 0; c < CH; ++c) {
            float4 r4 = ((const float4*)(refimg + (size_t)c * HH))[q];
            float4 t4 = ((const float4*)(tgtimg + (size_t)c * HH))[q];
            rv[c][0] = r4.x; rv[c][1] = r4.y; rv[c][2] = r4.z; rv[c][3] = r4.w;
            tv[c][0] = t4.x; tv[c][1] = t4.y; tv[c][2] = t4.z; tv[c][3] = t4.w;
        }

        #pragma unroll
        for (int e = 0; e < 4; ++e) {
            if (cd[e]) {
                float m = ms[e];
                #pragma unroll
                for (int c = 0; c < CH; ++c) {
                    float v = (rv[c][e] * 0.5f + 0.5f) * 255.0f * m;  // m==0 -> bin 0
                    atomicAdd(&hd[c * BINS + bin_of(v)], cd[e]);
                }
            }
            if (cr[e]) {
                float m = mt[e];
                #pragma unroll
                for (int c = 0; c < CH; ++c) {
                    float v = (tv[c][e] * 0.5f + 0.5f) * 255.0f * m;
                    atomicAdd(&hr[c * BINS + bin_of(v)], cr[e]);
                }
            }
        }
    }

    __syncthreads();
    for (int i = threadIdx.x; i < CH * BINS; i += 256) {
        unsigned int v = hd[i];
        if (v) atomicAdd(&hist_dst[i], v);
        v = hr[i];
        if (v) atomicAdd(&hist_ref[i], v);
    }
}

__global__ __launch_bounds__(256) void table_kernel(
    const unsigned int* __restrict__ hist_dst,
    const unsigned int* __restrict__ hist_ref,
    int* __restrict__ table)
{
    __shared__ float cd[CH * BINS];
    __shared__ float cr[CH * BINS];
    const int i = threadIdx.x;  // 0..255
    for (int t = i; t < CH * BINS; t += 256) {
        cd[t] = (float)hist_dst[t];
        cr[t] = (float)hist_ref[t];
    }
    __syncthreads();

    // cumsum computed redundantly per thread; all LDS reads are broadcast
    // (every thread reads the same address each step). f32 add order matches
    // the reference's sequential cumsum exactly.
    float myd[CH], myr[CH];
    #pragma unroll
    for (int c = 0; c < CH; ++c) {
        float run = 0.0f, mine = 0.0f;
        for (int k = 0; k < BINS; ++k) { run += cd[c * BINS + k]; if (k == i) mine = run; }
        myd[c] = mine / run;
        run = 0.0f; mine = 0.0f;
        for (int k = 0; k < BINS; ++k) { run += cr[c * BINS + k]; if (k == i) mine = run; }
        myr[c] = mine / run;
    }
    __syncthreads();
    #pragma unroll
    for (int c = 0; c < CH; ++c) {
        cd[c * BINS + i] = myd[c];
        cr[c * BINS + i] = myr[c];
    }
    __syncthreads();

    #pragma unroll
    for (int c = 0; c < CH; ++c) {
        int t;
        if (i == 0) t = 0;
        else if (i == BINS - 1) t = BINS - 1;
        else {
            float r = cd[c * BINS + i];
            t = i;  // not-found default
            for (int j = 0; j < BINS - 1; ++j) {
                float lo = cr[c * BINS + j];
                float hi = cr[c * BINS + j + 1];
                if (lo <= r && r <= hi) { t = j + 1; break; }
            }
        }
        table[c * BINS + i] = t;
    }
}

__global__ __launch_bounds__(256) void loss_kernel(
    const float* __restrict__ input, const float* __restrict__ refimg,
    const float* __restrict__ mask_src, const unsigned int* __restrict__ cnt_dst,
    const int* __restrict__ table, double* __restrict__ acc)
{
    __shared__ int tab[CH * BINS];
    for (int i = threadIdx.x; i < CH * BINS; i += 256) tab[i] = table[i];
    __syncthreads();

    float lsum = 0.0f;
    const int nq = HH / 4;
    const int stride = gridDim.x * 256;
    for (int q = blockIdx.x * 256 + threadIdx.x; q < nq; q += stride) {
        float4 m4 = ((const float4*)mask_src)[q];
        uint2 w = ((const uint2*)cnt_dst)[q];
        const unsigned int sel[4] = { w.x & 0xFFFFu, w.x >> 16, w.y & 0xFFFFu, w.y >> 16 };
        const float mm[4] = { m4.x, m4.y, m4.z, m4.w };
        #pragma unroll
        for (int c = 0; c < CH; ++c) {
            float4 a4 = ((const float4*)(input + (size_t)c * HH))[q];
            float4 r4 = ((const float4*)(refimg + (size_t)c * HH))[q];
            const float aa[4] = { a4.x, a4.y, a4.z, a4.w };
            const float rr[4] = { r4.x, r4.y, r4.z, r4.w };
            #pragma unroll
            for (int e = 0; e < 4; ++e) {
                float m = mm[e];
                float av = (aa[e] * 0.5f + 0.5f) * 255.0f * m;
                float rv = (rr[e] * 0.5f + 0.5f) * 255.0f * m;
                float tv = (float)tab[c * BINS + bin_of(rv)];
                float mv = m * (sel[e] ? tv : rv);
                lsum += fabsf(av - mv);
            }
        }
    }

    // block reduction in double
    double d = (double)lsum;
    #pragma unroll
    for (int off = 32; off; off >>= 1) d += __shfl_down(d, off);
    __shared__ double wsum[4];
    int wid = threadIdx.x >> 6;
    int lane = threadIdx.x & 63;
    if (lane == 0) wsum[wid] = d;
    __syncthreads();
    if (threadIdx.x == 0) {
        double t = wsum[0] + wsum[1] + wsum[2] + wsum[3];
        atomicAdd(acc, t);
    }
}

__global__ void finalize_kernel(const double* __restrict__ acc, float* __restrict__ out)
{
    if (threadIdx.x == 0 && blockIdx.x == 0) {
        out[0] = (float)(acc[0] / (double)(CH * (double)HH));
    }
}

extern "C" void kernel_launch(void* const* d_in, const int* in_sizes, int n_in,
                              void* d_out, int out_size, void* d_ws, size_t ws_size,
                              hipStream_t stream)
{
    const float* input    = (const float*)d_in[0];
    const float* target   = (const float*)d_in[1];
    const float* mask_src = (const float*)d_in[2];
    const float* mask_tar = (const float*)d_in[3];
    const int*   idx0     = (const int*)d_in[4];
    const int*   idx1     = (const int*)d_in[5];
    const int*   idx2     = (const int*)d_in[6];
    const int*   idx3     = (const int*)d_in[7];
    const float* refimg   = (const float*)d_in[8];

    char* ws = (char*)d_ws;
    unsigned int* hist_dst = (unsigned int*)(ws + WS_HIST_DST);
    unsigned int* hist_ref = (unsigned int*)(ws + WS_HIST_REF);
    int*          table    = (int*)(ws + WS_TABLE);
    double*       acc      = (double*)(ws + WS_ACC);
    unsigned int* cnt_dst  = (unsigned int*)(ws + WS_CNT_DST);
    unsigned int* cnt_ref  = (unsigned int*)(ws + WS_CNT_REF);

    hipMemsetAsync(d_ws, 0, WS_ZERO_BYTES, stream);

    scatter_kernel<<<2048, 256, 0, stream>>>((const int4*)idx0, (const int4*)idx1,
                                             (const int4*)idx2, (const int4*)idx3,
                                             cnt_dst, cnt_ref);
    sweep_kernel<<<1024, 256, 0, stream>>>(mask_src, mask_tar, refimg, target,
                                           cnt_dst, cnt_ref, hist_dst, hist_ref);
    table_kernel<<<1, 256, 0, stream>>>(hist_dst, hist_ref, table);
    loss_kernel<<<2048, 256, 0, stream>>>(input, refimg, mask_src, cnt_dst, table, acc);
    finalize_kernel<<<1, 64, 0, stream>>>(acc, (float*)d_out);
}

// Round 3
// 488.540 us; speedup vs baseline: 1.0530x; 1.0496x over previous
//
#include <hip/hip_runtime.h>

#define H 2048
#define HH (H * H)
#define NIDX 2097152
#define BINS 256
#define CH 3

// ws layout
// 0        : uint hist_dst[3][256]   (3072 B)
// 3072     : uint hist_ref[3][256]   (3072 B)
// 6144     : int  table[3][256]      (3072 B)
// 9216     : double acc              (8 B)
// 16384    : uint cnt_dst[HH/2]      (2x16-bit packed counts, 8.4 MB)  [zeroed]
// +HH*2    : uint binpack_ref[HH]    (16.8 MB, fully written by prep)  [not zeroed]
#define WS_HIST_DST 0
#define WS_HIST_REF 3072
#define WS_TABLE    6144
#define WS_ACC      9216
#define WS_CNT_DST  16384
#define WS_BINPACK  (16384 + (size_t)HH * 2)
#define WS_ZERO_BYTES (16384 + (size_t)HH * 2)

__device__ __forceinline__ int bin_of(float v) {
    int b = (int)floorf(v);
    return min(max(b, 0), BINS - 1);
}

// 16-bit packed counter increment: pixel p lives in word p>>1, half p&1.
__device__ __forceinline__ void cnt_inc(unsigned int* cnt, int p) {
    atomicAdd(&cnt[p >> 1], (p & 1) ? 0x10000u : 1u);
}

// Coalesced pass over target side: per-pixel packed 3-channel bin word.
// mask==1 -> value in [127.5,255) -> bin in [127,254] (never 0), so
// word==0  <=>  mask==0 (all channels bin 0).
__global__ __launch_bounds__(256) void prep_kernel(
    const float* __restrict__ mask_tar, const float* __restrict__ tgtimg,
    unsigned int* __restrict__ binpack)
{
    const int nq = HH / 4;
    const int stride = gridDim.x * 256;
    for (int q = blockIdx.x * 256 + threadIdx.x; q < nq; q += stride) {
        float4 m4 = ((const float4*)mask_tar)[q];
        const float mm[4] = { m4.x, m4.y, m4.z, m4.w };
        unsigned int w[4] = { 0u, 0u, 0u, 0u };
        #pragma unroll
        for (int c = 0; c < CH; ++c) {
            float4 t4 = ((const float4*)(tgtimg + (size_t)c * HH))[q];
            const float tt[4] = { t4.x, t4.y, t4.z, t4.w };
            #pragma unroll
            for (int e = 0; e < 4; ++e) {
                float v = (tt[e] * 0.5f + 0.5f) * 255.0f * mm[e];
                w[e] |= ((unsigned int)bin_of(v)) << (8 * c);
            }
        }
        uint4 out = { w[0], w[1], w[2], w[3] };
        ((uint4*)binpack)[q] = out;
    }
}

__global__ __launch_bounds__(256) void scatter_kernel(
    const int4* __restrict__ idx0, const int4* __restrict__ idx1,
    const int4* __restrict__ idx2, const int4* __restrict__ idx3,
    const unsigned int* __restrict__ binpack,
    unsigned int* __restrict__ cnt_dst, unsigned int* __restrict__ hist_ref)
{
    __shared__ unsigned int hr[CH * BINS];
    for (int i = threadIdx.x; i < CH * BINS; i += 256) hr[i] = 0u;
    __syncthreads();

    unsigned int zc = 0;  // ref-side samples with mask==0 (all 3 channels -> bin 0)
    const int n4 = NIDX / 4;
    const int stride = gridDim.x * 256;
    for (int k = blockIdx.x * 256 + threadIdx.x; k < n4; k += stride) {
        int4 a = idx0[k], b = idx1[k], c = idx2[k], d = idx3[k];
        // issue the 4 random reads first so they're in flight over the atomics
        int p0 = c.x * H + d.x, p1 = c.y * H + d.y;
        int p2 = c.z * H + d.z, p3 = c.w * H + d.w;
        unsigned int w0 = binpack[p0], w1 = binpack[p1];
        unsigned int w2 = binpack[p2], w3 = binpack[p3];

        cnt_inc(cnt_dst, a.x * H + b.x);
        cnt_inc(cnt_dst, a.y * H + b.y);
        cnt_inc(cnt_dst, a.z * H + b.z);
        cnt_inc(cnt_dst, a.w * H + b.w);

        const unsigned int ws[4] = { w0, w1, w2, w3 };
        #pragma unroll
        for (int e = 0; e < 4; ++e) {
            unsigned int w = ws[e];
            if (w == 0u) {
                ++zc;
            } else {
                atomicAdd(&hr[0 * BINS + (w & 0xFFu)], 1u);
                atomicAdd(&hr[1 * BINS + ((w >> 8) & 0xFFu)], 1u);
                atomicAdd(&hr[2 * BINS + ((w >> 16) & 0xFFu)], 1u);
            }
        }
    }

    // wave-reduce zc, one LDS atomic per wave per channel
    int z = (int)zc;
    #pragma unroll
    for (int off = 32; off; off >>= 1) z += __shfl_down(z, off);
    if ((threadIdx.x & 63) == 0 && z) {
        atomicAdd(&hr[0 * BINS], (unsigned int)z);
        atomicAdd(&hr[1 * BINS], (unsigned int)z);
        atomicAdd(&hr[2 * BINS], (unsigned int)z);
    }

    __syncthreads();
    for (int i = threadIdx.x; i < CH * BINS; i += 256) {
        unsigned int v = hr[i];
        if (v) atomicAdd(&hist_ref[i], v);
    }
}

// dst side only: weight per-pixel bins by scatter counts.
__global__ __launch_bounds__(256) void sweep_kernel(
    const float* __restrict__ mask_src, const float* __restrict__ refimg,
    const unsigned int* __restrict__ cnt_dst,
    unsigned int* __restrict__ hist_dst)
{
    __shared__ unsigned int hd[CH * BINS];
    for (int i = threadIdx.x; i < CH * BINS; i += 256) hd[i] = 0u;
    __syncthreads();

    unsigned int zc = 0;  // mask==0 pixels: all 3 channels -> bin 0, weight cd
    const int nq = HH / 4;
    const int stride = gridDim.x * 256;
    for (int q = blockIdx.x * 256 + threadIdx.x; q < nq; q += stride) {
        uint2 wd = ((const uint2*)cnt_dst)[q];
        unsigned int cd[4] = { wd.x & 0xFFFFu, wd.x >> 16, wd.y & 0xFFFFu, wd.y >> 16 };
        float4 ms4 = ((const float4*)mask_src)[q];
        const float ms[4] = { ms4.x, ms4.y, ms4.z, ms4.w };

        float rv[CH][4];
        #pragma unroll
        for (int c = 0; c < CH; ++c) {
            float4 r4 = ((const float4*)(refimg + (size_t)c * HH))[q];
            rv[c][0] = r4.x; rv[c][1] = r4.y; rv[c][2] = r4.z; rv[c][3] = r4.w;
        }

        #pragma unroll
        for (int e = 0; e < 4; ++e) {
            if (cd[e]) {
                if (ms[e] == 0.0f) {
                    zc += cd[e];
                } else {
                    #pragma unroll
                    for (int c = 0; c < CH; ++c) {
                        float v = (rv[c][e] * 0.5f + 0.5f) * 255.0f;  // m==1
                        atomicAdd(&hd[c * BINS + bin_of(v)], cd[e]);
                    }
                }
            }
        }
    }

    int z = (int)zc;
    #pragma unroll
    for (int off = 32; off; off >>= 1) z += __shfl_down(z, off);
    if ((threadIdx.x & 63) == 0 && z) {
        atomicAdd(&hd[0 * BINS], (unsigned int)z);
        atomicAdd(&hd[1 * BINS], (unsigned int)z);
        atomicAdd(&hd[2 * BINS], (unsigned int)z);
    }

    __syncthreads();
    for (int i = threadIdx.x; i < CH * BINS; i += 256) {
        unsigned int v = hd[i];
        if (v) atomicAdd(&hist_dst[i], v);
    }
}

__global__ __launch_bounds__(256) void table_kernel(
    const unsigned int* __restrict__ hist_dst,
    const unsigned int* __restrict__ hist_ref,
    int* __restrict__ table)
{
    __shared__ float cd[CH * BINS];
    __shared__ float cr[CH * BINS];
    const int i = threadIdx.x;  // 0..255
    for (int t = i; t < CH * BINS; t += 256) {
        cd[t] = (float)hist_dst[t];
        cr[t] = (float)hist_ref[t];
    }
    __syncthreads();

    // cumsum computed redundantly per thread; all LDS reads broadcast.
    // f32 add order matches the reference's sequential cumsum exactly.
    float myd[CH], myr[CH];
    #pragma unroll
    for (int c = 0; c < CH; ++c) {
        float run = 0.0f, mine = 0.0f;
        for (int k = 0; k < BINS; ++k) { run += cd[c * BINS + k]; if (k == i) mine = run; }
        myd[c] = mine / run;
        run = 0.0f; mine = 0.0f;
        for (int k = 0; k < BINS; ++k) { run += cr[c * BINS + k]; if (k == i) mine = run; }
        myr[c] = mine / run;
    }
    __syncthreads();
    #pragma unroll
    for (int c = 0; c < CH; ++c) {
        cd[c * BINS + i] = myd[c];
        cr[c * BINS + i] = myr[c];
    }
    __syncthreads();

    #pragma unroll
    for (int c = 0; c < CH; ++c) {
        int t;
        if (i == 0) t = 0;
        else if (i == BINS - 1) t = BINS - 1;
        else {
            float r = cd[c * BINS + i];
            t = i;  // not-found default
            for (int j = 0; j < BINS - 1; ++j) {
                float lo = cr[c * BINS + j];
                float hi = cr[c * BINS + j + 1];
                if (lo <= r && r <= hi) { t = j + 1; break; }
            }
        }
        table[c * BINS + i] = t;
    }
}

__global__ __launch_bounds__(256) void loss_kernel(
    const float* __restrict__ input, const float* __restrict__ refimg,
    const float* __restrict__ mask_src, const unsigned int* __restrict__ cnt_dst,
    const int* __restrict__ table, double* __restrict__ acc)
{
    __shared__ int tab[CH * BINS];
    for (int i = threadIdx.x; i < CH * BINS; i += 256) tab[i] = table[i];
    __syncthreads();

    float lsum = 0.0f;
    const int nq = HH / 4;
    const int stride = gridDim.x * 256;
    for (int q = blockIdx.x * 256 + threadIdx.x; q < nq; q += stride) {
        float4 m4 = ((const float4*)mask_src)[q];
        uint2 w = ((const uint2*)cnt_dst)[q];
        const unsigned int sel[4] = { w.x & 0xFFFFu, w.x >> 16, w.y & 0xFFFFu, w.y >> 16 };
        const float mm[4] = { m4.x, m4.y, m4.z, m4.w };
        #pragma unroll
        for (int c = 0; c < CH; ++c) {
            float4 a4 = ((const float4*)(input + (size_t)c * HH))[q];
            float4 r4 = ((const float4*)(refimg + (size_t)c * HH))[q];
            const float aa[4] = { a4.x, a4.y, a4.z, a4.w };
            const float rr[4] = { r4.x, r4.y, r4.z, r4.w };
            #pragma unroll
            for (int e = 0; e < 4; ++e) {
                float m = mm[e];
                float av = (aa[e] * 0.5f + 0.5f) * 255.0f * m;
                float rv = (rr[e] * 0.5f + 0.5f) * 255.0f * m;
                float tv = (float)tab[c * BINS + bin_of(rv)];
                float mv = m * (sel[e] ? tv : rv);
                lsum += fabsf(av - mv);
            }
        }
    }

    double d = (double)lsum;
    #pragma unroll
    for (int off = 32; off; off >>= 1) d += __shfl_down(d, off);
    __shared__ double wsum[4];
    int wid = threadIdx.x >> 6;
    int lane = threadIdx.x & 63;
    if (lane == 0) wsum[wid] = d;
    __syncthreads();
    if (threadIdx.x == 0) {
        double t = wsum[0] + wsum[1] + wsum[2] + wsum[3];
        atomicAdd(acc, t);
    }
}

__global__ void finalize_kernel(const double* __restrict__ acc, float* __restrict__ out)
{
    if (threadIdx.x == 0 && blockIdx.x == 0) {
        out[0] = (float)(acc[0] / (double)(CH * (double)HH));
    }
}

extern "C" void kernel_launch(void* const* d_in, const int* in_sizes, int n_in,
                              void* d_out, int out_size, void* d_ws, size_t ws_size,
                              hipStream_t stream)
{
    const float* input    = (const float*)d_in[0];
    const float* target   = (const float*)d_in[1];
    const float* mask_src = (const float*)d_in[2];
    const float* mask_tar = (const float*)d_in[3];
    const int*   idx0     = (const int*)d_in[4];
    const int*   idx1     = (const int*)d_in[5];
    const int*   idx2     = (const int*)d_in[6];
    const int*   idx3     = (const int*)d_in[7];
    const float* refimg   = (const float*)d_in[8];

    char* ws = (char*)d_ws;
    unsigned int* hist_dst = (unsigned int*)(ws + WS_HIST_DST);
    unsigned int* hist_ref = (unsigned int*)(ws + WS_HIST_REF);
    int*          table    = (int*)(ws + WS_TABLE);
    double*       acc      = (double*)(ws + WS_ACC);
    unsigned int* cnt_dst  = (unsigned int*)(ws + WS_CNT_DST);
    unsigned int* binpack  = (unsigned int*)(ws + WS_BINPACK);

    hipMemsetAsync(d_ws, 0, WS_ZERO_BYTES, stream);

    prep_kernel<<<2048, 256, 0, stream>>>(mask_tar, target, binpack);
    scatter_kernel<<<2048, 256, 0, stream>>>((const int4*)idx0, (const int4*)idx1,
                                             (const int4*)idx2, (const int4*)idx3,
                                             binpack, cnt_dst, hist_ref);
    sweep_kernel<<<1024, 256, 0, stream>>>(mask_src, refimg, cnt_dst, hist_dst);
    table_kernel<<<1, 256, 0, stream>>>(hist_dst, hist_ref, table);
    loss_kernel<<<2048, 256, 0, stream>>>(input, refimg, mask_src, cnt_dst, table, acc);
    finalize_kernel<<<1, 64, 0, stream>>>(acc, (float*)d_out);
}

// Round 4
// 442.287 us; speedup vs baseline: 1.1631x; 1.1046x over previous
//
#include <hip/hip_runtime.h>

#define H 2048
#define HH (H * H)
#define NIDX 2097152
#define BINS 256
#define CH 3

// ---------------- main-path ws layout ----------------
#define NBUCK 64          // pixel-space buckets (p>>16), 256KB binpack slice each
#define NLIST 128         // 2 sides x 64 buckets
#define CAPG  139264      // per-list capacity: mean 131072, sigma~360, +big margin
#define WS_HIST_DST 0
#define WS_HIST_REF 3072
#define WS_TABLE    6144
#define WS_ACC      9216
#define WS_CURS     9728                        // uint[128]
#define WS_CTRL_BYTES 16384                     // zeroed each call
#define WS_SEL      16384                       // uchar[HH] (zeroed by prep)
#define WS_BPS      (16384 + (size_t)HH)        // uint[HH] binpack_src
#define WS_BPR      (WS_BPS + (size_t)HH * 4)   // uint[HH] binpack_ref
#define WS_LIST     (WS_BPR + (size_t)HH * 4)   // ushort[NLIST*CAPG]
#define WS_MAIN_BYTES (WS_LIST + (size_t)NLIST * CAPG * 2)

// ---------------- fallback (R3) ws layout ----------------
#define FB_CNT_DST  16384
#define FB_BINPACK  (16384 + (size_t)HH * 2)
#define FB_ZERO_BYTES (16384 + (size_t)HH * 2)

__device__ __forceinline__ int bin_of(float v) {
    int b = (int)floorf(v);
    return min(max(b, 0), BINS - 1);
}

// ============================================================
// MAIN PATH
// ============================================================

// Coalesced pass: packed 3-channel bin words for both sides + zero selected.
// mask==1 -> value in [127.5,255) -> bin in [127,254] (never 0), so
// word==0  <=>  mask==0.
__global__ __launch_bounds__(256) void prep_main(
    const float* __restrict__ mask_src, const float* __restrict__ mask_tar,
    const float* __restrict__ refimg, const float* __restrict__ tgtimg,
    unsigned int* __restrict__ bps, unsigned int* __restrict__ bpr,
    unsigned int* __restrict__ sel4)
{
    const int nq = HH / 4;
    const int stride = gridDim.x * 256;
    for (int q = blockIdx.x * 256 + threadIdx.x; q < nq; q += stride) {
        float4 ms4 = ((const float4*)mask_src)[q];
        float4 mt4 = ((const float4*)mask_tar)[q];
        const float ms[4] = { ms4.x, ms4.y, ms4.z, ms4.w };
        const float mt[4] = { mt4.x, mt4.y, mt4.z, mt4.w };
        unsigned int wsrc[4] = { 0u, 0u, 0u, 0u };
        unsigned int wref[4] = { 0u, 0u, 0u, 0u };
        #pragma unroll
        for (int c = 0; c < CH; ++c) {
            float4 r4 = ((const float4*)(refimg + (size_t)c * HH))[q];
            float4 t4 = ((const float4*)(tgtimg + (size_t)c * HH))[q];
            const float rr[4] = { r4.x, r4.y, r4.z, r4.w };
            const float tt[4] = { t4.x, t4.y, t4.z, t4.w };
            #pragma unroll
            for (int e = 0; e < 4; ++e) {
                float vs = (rr[e] * 0.5f + 0.5f) * 255.0f * ms[e];
                float vt = (tt[e] * 0.5f + 0.5f) * 255.0f * mt[e];
                wsrc[e] |= ((unsigned int)bin_of(vs)) << (8 * c);
                wref[e] |= ((unsigned int)bin_of(vt)) << (8 * c);
            }
        }
        uint4 o1 = { wsrc[0], wsrc[1], wsrc[2], wsrc[3] };
        uint4 o2 = { wref[0], wref[1], wref[2], wref[3] };
        ((uint4*)bps)[q] = o1;
        ((uint4*)bpr)[q] = o2;
        sel4[q] = 0u;
    }
}

// Bucket all sample positions by p>>16 via LDS staging.
#define P1_BLOCKS 512
#define P1_SPB (NIDX / P1_BLOCKS)   // 4096 samples/block
#define P1_CAP 128                  // per-list LDS capacity (mean fill 64)

__global__ __launch_bounds__(256) void partition_kernel(
    const int* __restrict__ idx0, const int* __restrict__ idx1,
    const int* __restrict__ idx2, const int* __restrict__ idx3,
    unsigned short* __restrict__ list_g, unsigned int* __restrict__ curs)
{
    __shared__ unsigned short stage[NLIST * P1_CAP];   // 32 KB
    __shared__ unsigned int lcnt[NLIST];
    __shared__ unsigned int lbase[NLIST];
    for (int i = threadIdx.x; i < NLIST; i += 256) lcnt[i] = 0u;
    __syncthreads();

    const int base_k = blockIdx.x * P1_SPB;
    for (int r = 0; r < P1_SPB / 256; ++r) {
        int k = base_k + r * 256 + threadIdx.x;
        int pd = idx0[k] * H + idx1[k];
        int pr = idx2[k] * H + idx3[k];
        {
            int l = pd >> 16;  // 0..63
            unsigned int pos = atomicAdd(&lcnt[l], 1u);
            if (pos < P1_CAP) stage[l * P1_CAP + pos] = (unsigned short)(pd & 0xFFFF);
            else {  // statistically ~impossible overflow slow path
                unsigned int g = atomicAdd(&curs[l], 1u);
                if (g < CAPG) list_g[(size_t)l * CAPG + g] = (unsigned short)(pd & 0xFFFF);
            }
        }
        {
            int l = 64 + (pr >> 16);
            unsigned int pos = atomicAdd(&lcnt[l], 1u);
            if (pos < P1_CAP) stage[l * P1_CAP + pos] = (unsigned short)(pr & 0xFFFF);
            else {
                unsigned int g = atomicAdd(&curs[l], 1u);
                if (g < CAPG) list_g[(size_t)l * CAPG + g] = (unsigned short)(pr & 0xFFFF);
            }
        }
    }
    __syncthreads();
    if (threadIdx.x < NLIST) {
        unsigned int n = min(lcnt[threadIdx.x], (unsigned int)P1_CAP);
        lbase[threadIdx.x] = atomicAdd(&curs[threadIdx.x], n);
    }
    __syncthreads();
    for (int b = 0; b < NLIST; ++b) {
        int n = (int)min(lcnt[b], (unsigned int)P1_CAP);
        unsigned int gb = lbase[b];
        for (int e = threadIdx.x; e < n; e += 256) {
            unsigned int gi = gb + e;
            if (gi < CAPG) list_g[(size_t)b * CAPG + gi] = stage[b * P1_CAP + e];
        }
    }
}

// XCD-localized gather: block b -> xcd b%8 -> buckets [8*xcd, 8*xcd+8).
// Random reads confined to ~0.6 MB per XCD per phase -> L2-resident.
__global__ __launch_bounds__(256) void gather_hist_kernel(
    const unsigned short* __restrict__ list_g, const unsigned int* __restrict__ curs,
    const unsigned int* __restrict__ bps, const unsigned int* __restrict__ bpr,
    unsigned char* __restrict__ selected,
    unsigned int* __restrict__ hist_dst, unsigned int* __restrict__ hist_ref)
{
    __shared__ unsigned int hd[CH * BINS];
    __shared__ unsigned int hr[CH * BINS];
    for (int i = threadIdx.x; i < CH * BINS; i += 256) { hd[i] = 0u; hr[i] = 0u; }
    __syncthreads();

    const int xcd = blockIdx.x & 7;
    const int j = blockIdx.x >> 3;   // 0..255 (grid 2048)
    unsigned int zc_d = 0, zc_r = 0;

    for (int phase = 0; phase < 8; ++phase) {
        const int bucket = xcd * 8 + phase;
        const unsigned int pbase = ((unsigned int)bucket) << 16;
        // dst side: histogram + selected mark
        {
            const int l = bucket;
            unsigned int n = min(curs[l], (unsigned int)CAPG);
            unsigned int chunk = (n + 255u) >> 8;
            unsigned int s = j * chunk;
            unsigned int e = min(s + chunk, n);
            for (unsigned int i = s + threadIdx.x; i < e; i += 256) {
                unsigned int p = pbase | (unsigned int)list_g[(size_t)l * CAPG + i];
                unsigned int w = bps[p];
                selected[p] = 1;
                if (w == 0u) ++zc_d;
                else {
                    atomicAdd(&hd[0 * BINS + (w & 0xFFu)], 1u);
                    atomicAdd(&hd[1 * BINS + ((w >> 8) & 0xFFu)], 1u);
                    atomicAdd(&hd[2 * BINS + ((w >> 16) & 0xFFu)], 1u);
                }
            }
        }
        // ref side
        {
            const int l = 64 + bucket;
            unsigned int n = min(curs[l], (unsigned int)CAPG);
            unsigned int chunk = (n + 255u) >> 8;
            unsigned int s = j * chunk;
            unsigned int e = min(s + chunk, n);
            for (unsigned int i = s + threadIdx.x; i < e; i += 256) {
                unsigned int p = pbase | (unsigned int)list_g[(size_t)l * CAPG + i];
                unsigned int w = bpr[p];
                if (w == 0u) ++zc_r;
                else {
                    atomicAdd(&hr[0 * BINS + (w & 0xFFu)], 1u);
                    atomicAdd(&hr[1 * BINS + ((w >> 8) & 0xFFu)], 1u);
                    atomicAdd(&hr[2 * BINS + ((w >> 16) & 0xFFu)], 1u);
                }
            }
        }
    }

    int zd = (int)zc_d, zr = (int)zc_r;
    #pragma unroll
    for (int off = 32; off; off >>= 1) { zd += __shfl_down(zd, off); zr += __shfl_down(zr, off); }
    if ((threadIdx.x & 63) == 0) {
        if (zd) {
            atomicAdd(&hd[0 * BINS], (unsigned int)zd);
            atomicAdd(&hd[1 * BINS], (unsigned int)zd);
            atomicAdd(&hd[2 * BINS], (unsigned int)zd);
        }
        if (zr) {
            atomicAdd(&hr[0 * BINS], (unsigned int)zr);
            atomicAdd(&hr[1 * BINS], (unsigned int)zr);
            atomicAdd(&hr[2 * BINS], (unsigned int)zr);
        }
    }

    __syncthreads();
    for (int i = threadIdx.x; i < CH * BINS; i += 256) {
        unsigned int v = hd[i];
        if (v) atomicAdd(&hist_dst[i], v);
        v = hr[i];
        if (v) atomicAdd(&hist_ref[i], v);
    }
}

// Parallel scan table build. Exact: all partial sums are integers < 2^24,
// representable in f32 under ANY summation order -> bit-identical to the
// reference's sequential cumsum.
__global__ __launch_bounds__(256) void table_kernel(
    const unsigned int* __restrict__ hist_dst,
    const unsigned int* __restrict__ hist_ref,
    int* __restrict__ table)
{
    __shared__ float cd[CH * BINS];
    __shared__ float cr[CH * BINS];
    __shared__ float tmp[BINS];
    __shared__ float tot_s;
    const int i = threadIdx.x;  // 0..255

    for (int a = 0; a < 6; ++a) {
        const unsigned int* h = (a < 3) ? (hist_dst + a * BINS) : (hist_ref + (a - 3) * BINS);
        float* out = (a < 3) ? (cd + a * BINS) : (cr + (a - 3) * BINS);
        float x = (float)h[i];
        tmp[i] = x;
        __syncthreads();
        #pragma unroll
        for (int off = 1; off < BINS; off <<= 1) {
            float y = (i >= off) ? tmp[i - off] : 0.0f;
            __syncthreads();
            x += y;
            tmp[i] = x;
            __syncthreads();
        }
        if (i == BINS - 1) tot_s = x;
        __syncthreads();
        out[i] = x / tot_s;
        __syncthreads();
    }

    #pragma unroll
    for (int c = 0; c < CH; ++c) {
        int t;
        if (i == 0) t = 0;
        else if (i == BINS - 1) t = BINS - 1;
        else {
            float r = cd[c * BINS + i];
            t = i;  // not-found default
            for (int jj = 0; jj < BINS - 1; ++jj) {
                float lo = cr[c * BINS + jj];
                float hi = cr[c * BINS + jj + 1];
                if (lo <= r && r <= hi) { t = jj + 1; break; }
            }
        }
        table[c * BINS + i] = t;
    }
}

__global__ __launch_bounds__(256) void loss_sel_kernel(
    const float* __restrict__ input, const float* __restrict__ refimg,
    const float* __restrict__ mask_src, const unsigned char* __restrict__ selected,
    const int* __restrict__ table, double* __restrict__ acc)
{
    __shared__ int tab[CH * BINS];
    for (int i = threadIdx.x; i < CH * BINS; i += 256) tab[i] = table[i];
    __syncthreads();

    float lsum = 0.0f;
    const int nq = HH / 4;
    const int stride = gridDim.x * 256;
    for (int q = blockIdx.x * 256 + threadIdx.x; q < nq; q += stride) {
        float4 m4 = ((const float4*)mask_src)[q];
        uchar4 s4 = ((const uchar4*)selected)[q];
        const unsigned char ss[4] = { s4.x, s4.y, s4.z, s4.w };
        const float mm[4] = { m4.x, m4.y, m4.z, m4.w };
        #pragma unroll
        for (int c = 0; c < CH; ++c) {
            float4 a4 = ((const float4*)(input + (size_t)c * HH))[q];
            float4 r4 = ((const float4*)(refimg + (size_t)c * HH))[q];
            const float aa[4] = { a4.x, a4.y, a4.z, a4.w };
            const float rr[4] = { r4.x, r4.y, r4.z, r4.w };
            #pragma unroll
            for (int e = 0; e < 4; ++e) {
                float m = mm[e];
                float av = (aa[e] * 0.5f + 0.5f) * 255.0f * m;
                float rv = (rr[e] * 0.5f + 0.5f) * 255.0f * m;
                float tv = (float)tab[c * BINS + bin_of(rv)];
                float mv = m * (ss[e] ? tv : rv);
                lsum += fabsf(av - mv);
            }
        }
    }

    double d = (double)lsum;
    #pragma unroll
    for (int off = 32; off; off >>= 1) d += __shfl_down(d, off);
    __shared__ double wsum[4];
    int wid = threadIdx.x >> 6;
    int lane = threadIdx.x & 63;
    if (lane == 0) wsum[wid] = d;
    __syncthreads();
    if (threadIdx.x == 0) {
        double t = wsum[0] + wsum[1] + wsum[2] + wsum[3];
        atomicAdd(acc, t);
    }
}

__global__ void finalize_kernel(const double* __restrict__ acc, float* __restrict__ out)
{
    if (threadIdx.x == 0 && blockIdx.x == 0) {
        out[0] = (float)(acc[0] / (double)(CH * (double)HH));
    }
}

// ============================================================
// FALLBACK PATH (proven R3 pipeline) — used if ws_size too small
// ============================================================

__device__ __forceinline__ void cnt_inc(unsigned int* cnt, int p) {
    atomicAdd(&cnt[p >> 1], (p & 1) ? 0x10000u : 1u);
}

__global__ __launch_bounds__(256) void fb_prep_kernel(
    const float* __restrict__ mask_tar, const float* __restrict__ tgtimg,
    unsigned int* __restrict__ binpack)
{
    const int nq = HH / 4;
    const int stride = gridDim.x * 256;
    for (int q = blockIdx.x * 256 + threadIdx.x; q < nq; q += stride) {
        float4 m4 = ((const float4*)mask_tar)[q];
        const float mm[4] = { m4.x, m4.y, m4.z, m4.w };
        unsigned int w[4] = { 0u, 0u, 0u, 0u };
        #pragma unroll
        for (int c = 0; c < CH; ++c) {
            float4 t4 = ((const float4*)(tgtimg + (size_t)c * HH))[q];
            const float tt[4] = { t4.x, t4.y, t4.z, t4.w };
            #pragma unroll
            for (int e = 0; e < 4; ++e) {
                float v = (tt[e] * 0.5f + 0.5f) * 255.0f * mm[e];
                w[e] |= ((unsigned int)bin_of(v)) << (8 * c);
            }
        }
        uint4 out = { w[0], w[1], w[2], w[3] };
        ((uint4*)binpack)[q] = out;
    }
}

__global__ __launch_bounds__(256) void fb_scatter_kernel(
    const int4* __restrict__ idx0, const int4* __restrict__ idx1,
    const int4* __restrict__ idx2, const int4* __restrict__ idx3,
    const unsigned int* __restrict__ binpack,
    unsigned int* __restrict__ cnt_dst, unsigned int* __restrict__ hist_ref)
{
    __shared__ unsigned int hr[CH * BINS];
    for (int i = threadIdx.x; i < CH * BINS; i += 256) hr[i] = 0u;
    __syncthreads();

    unsigned int zc = 0;
    const int n4 = NIDX / 4;
    const int stride = gridDim.x * 256;
    for (int k = blockIdx.x * 256 + threadIdx.x; k < n4; k += stride) {
        int4 a = idx0[k], b = idx1[k], c = idx2[k], d = idx3[k];
        int p0 = c.x * H + d.x, p1 = c.y * H + d.y;
        int p2 = c.z * H + d.z, p3 = c.w * H + d.w;
        unsigned int w0 = binpack[p0], w1 = binpack[p1];
        unsigned int w2 = binpack[p2], w3 = binpack[p3];

        cnt_inc(cnt_dst, a.x * H + b.x);
        cnt_inc(cnt_dst, a.y * H + b.y);
        cnt_inc(cnt_dst, a.z * H + b.z);
        cnt_inc(cnt_dst, a.w * H + b.w);

        const unsigned int ws2[4] = { w0, w1, w2, w3 };
        #pragma unroll
        for (int e = 0; e < 4; ++e) {
            unsigned int w = ws2[e];
            if (w == 0u) ++zc;
            else {
                atomicAdd(&hr[0 * BINS + (w & 0xFFu)], 1u);
                atomicAdd(&hr[1 * BINS + ((w >> 8) & 0xFFu)], 1u);
                atomicAdd(&hr[2 * BINS + ((w >> 16) & 0xFFu)], 1u);
            }
        }
    }

    int z = (int)zc;
    #pragma unroll
    for (int off = 32; off; off >>= 1) z += __shfl_down(z, off);
    if ((threadIdx.x & 63) == 0 && z) {
        atomicAdd(&hr[0 * BINS], (unsigned int)z);
        atomicAdd(&hr[1 * BINS], (unsigned int)z);
        atomicAdd(&hr[2 * BINS], (unsigned int)z);
    }

    __syncthreads();
    for (int i = threadIdx.x; i < CH * BINS; i += 256) {
        unsigned int v = hr[i];
        if (v) atomicAdd(&hist_ref[i], v);
    }
}

__global__ __launch_bounds__(256) void fb_sweep_kernel(
    const float* __restrict__ mask_src, const float* __restrict__ refimg,
    const unsigned int* __restrict__ cnt_dst,
    unsigned int* __restrict__ hist_dst)
{
    __shared__ unsigned int hd[CH * BINS];
    for (int i = threadIdx.x; i < CH * BINS; i += 256) hd[i] = 0u;
    __syncthreads();

    unsigned int zc = 0;
    const int nq = HH / 4;
    const int stride = gridDim.x * 256;
    for (int q = blockIdx.x * 256 + threadIdx.x; q < nq; q += stride) {
        uint2 wd = ((const uint2*)cnt_dst)[q];
        unsigned int cdc[4] = { wd.x & 0xFFFFu, wd.x >> 16, wd.y & 0xFFFFu, wd.y >> 16 };
        float4 ms4 = ((const float4*)mask_src)[q];
        const float ms[4] = { ms4.x, ms4.y, ms4.z, ms4.w };

        float rv[CH][4];
        #pragma unroll
        for (int c = 0; c < CH; ++c) {
            float4 r4 = ((const float4*)(refimg + (size_t)c * HH))[q];
            rv[c][0] = r4.x; rv[c][1] = r4.y; rv[c][2] = r4.z; rv[c][3] = r4.w;
        }
        #pragma unroll
        for (int e = 0; e < 4; ++e) {
            if (cdc[e]) {
                if (ms[e] == 0.0f) zc += cdc[e];
                else {
                    #pragma unroll
                    for (int c = 0; c < CH; ++c) {
                        float v = (rv[c][e] * 0.5f + 0.5f) * 255.0f;
                        atomicAdd(&hd[c * BINS + bin_of(v)], cdc[e]);
                    }
                }
            }
        }
    }

    int z = (int)zc;
    #pragma unroll
    for (int off = 32; off; off >>= 1) z += __shfl_down(z, off);
    if ((threadIdx.x & 63) == 0 && z) {
        atomicAdd(&hd[0 * BINS], (unsigned int)z);
        atomicAdd(&hd[1 * BINS], (unsigned int)z);
        atomicAdd(&hd[2 * BINS], (unsigned int)z);
    }

    __syncthreads();
    for (int i = threadIdx.x; i < CH * BINS; i += 256) {
        unsigned int v = hd[i];
        if (v) atomicAdd(&hist_dst[i], v);
    }
}

__global__ __launch_bounds__(256) void fb_loss_kernel(
    const float* __restrict__ input, const float* __restrict__ refimg,
    const float* __restrict__ mask_src, const unsigned int* __restrict__ cnt_dst,
    const int* __restrict__ table, double* __restrict__ acc)
{
    __shared__ int tab[CH * BINS];
    for (int i = threadIdx.x; i < CH * BINS; i += 256) tab[i] = table[i];
    __syncthreads();

    float lsum = 0.0f;
    const int nq = HH / 4;
    const int stride = gridDim.x * 256;
    for (int q = blockIdx.x * 256 + threadIdx.x; q < nq; q += stride) {
        float4 m4 = ((const float4*)mask_src)[q];
        uint2 w = ((const uint2*)cnt_dst)[q];
        const unsigned int sel[4] = { w.x & 0xFFFFu, w.x >> 16, w.y & 0xFFFFu, w.y >> 16 };
        const float mm[4] = { m4.x, m4.y, m4.z, m4.w };
        #pragma unroll
        for (int c = 0; c < CH; ++c) {
            float4 a4 = ((const float4*)(input + (size_t)c * HH))[q];
            float4 r4 = ((const float4*)(refimg + (size_t)c * HH))[q];
            const float aa[4] = { a4.x, a4.y, a4.z, a4.w };
            const float rr[4] = { r4.x, r4.y, r4.z, r4.w };
            #pragma unroll
            for (int e = 0; e < 4; ++e) {
                float m = mm[e];
                float av = (aa[e] * 0.5f + 0.5f) * 255.0f * m;
                float rv = (rr[e] * 0.5f + 0.5f) * 255.0f * m;
                float tv = (float)tab[c * BINS + bin_of(rv)];
                float mv = m * (sel[e] ? tv : rv);
                lsum += fabsf(av - mv);
            }
        }
    }

    double d = (double)lsum;
    #pragma unroll
    for (int off = 32; off; off >>= 1) d += __shfl_down(d, off);
    __shared__ double wsum[4];
    int wid = threadIdx.x >> 6;
    int lane = threadIdx.x & 63;
    if (lane == 0) wsum[wid] = d;
    __syncthreads();
    if (threadIdx.x == 0) {
        double t = wsum[0] + wsum[1] + wsum[2] + wsum[3];
        atomicAdd(acc, t);
    }
}

// ============================================================

extern "C" void kernel_launch(void* const* d_in, const int* in_sizes, int n_in,
                              void* d_out, int out_size, void* d_ws, size_t ws_size,
                              hipStream_t stream)
{
    const float* input    = (const float*)d_in[0];
    const float* target   = (const float*)d_in[1];
    const float* mask_src = (const float*)d_in[2];
    const float* mask_tar = (const float*)d_in[3];
    const int*   idx0     = (const int*)d_in[4];
    const int*   idx1     = (const int*)d_in[5];
    const int*   idx2     = (const int*)d_in[6];
    const int*   idx3     = (const int*)d_in[7];
    const float* refimg   = (const float*)d_in[8];

    char* ws = (char*)d_ws;
    unsigned int* hist_dst = (unsigned int*)(ws + WS_HIST_DST);
    unsigned int* hist_ref = (unsigned int*)(ws + WS_HIST_REF);
    int*          table    = (int*)(ws + WS_TABLE);
    double*       acc      = (double*)(ws + WS_ACC);

    if (ws_size >= WS_MAIN_BYTES) {
        unsigned int*   curs     = (unsigned int*)(ws + WS_CURS);
        unsigned char*  selected = (unsigned char*)(ws + WS_SEL);
        unsigned int*   bps      = (unsigned int*)(ws + WS_BPS);
        unsigned int*   bpr      = (unsigned int*)(ws + WS_BPR);
        unsigned short* list_g   = (unsigned short*)(ws + WS_LIST);

        hipMemsetAsync(d_ws, 0, WS_CTRL_BYTES, stream);
        prep_main<<<2048, 256, 0, stream>>>(mask_src, mask_tar, refimg, target,
                                            bps, bpr, (unsigned int*)selected);
        partition_kernel<<<P1_BLOCKS, 256, 0, stream>>>(idx0, idx1, idx2, idx3,
                                                        list_g, curs);
        gather_hist_kernel<<<2048, 256, 0, stream>>>(list_g, curs, bps, bpr,
                                                     selected, hist_dst, hist_ref);
        table_kernel<<<1, 256, 0, stream>>>(hist_dst, hist_ref, table);
        loss_sel_kernel<<<2048, 256, 0, stream>>>(input, refimg, mask_src,
                                                  selected, table, acc);
        finalize_kernel<<<1, 64, 0, stream>>>(acc, (float*)d_out);
    } else {
        unsigned int* cnt_dst = (unsigned int*)(ws + FB_CNT_DST);
        unsigned int* binpack = (unsigned int*)(ws + FB_BINPACK);

        hipMemsetAsync(d_ws, 0, FB_ZERO_BYTES, stream);
        fb_prep_kernel<<<2048, 256, 0, stream>>>(mask_tar, target, binpack);
        fb_scatter_kernel<<<2048, 256, 0, stream>>>((const int4*)idx0, (const int4*)idx1,
                                                    (const int4*)idx2, (const int4*)idx3,
                                                    binpack, cnt_dst, hist_ref);
        fb_sweep_kernel<<<1024, 256, 0, stream>>>(mask_src, refimg, cnt_dst, hist_dst);
        table_kernel<<<1, 256, 0, stream>>>(hist_dst, hist_ref, table);
        fb_loss_kernel<<<2048, 256, 0, stream>>>(input, refimg, mask_src, cnt_dst,
                                                 table, acc);
        finalize_kernel<<<1, 64, 0, stream>>>(acc, (float*)d_out);
    }
}

// Round 5
// 354.862 us; speedup vs baseline: 1.4497x; 1.2464x over previous
//
#include <hip/hip_runtime.h>

#define H 2048
#define HH (H * H)
#define NIDX 2097152
#define BINS 256
#define CH 3

// ---------------- main-path ws layout ----------------
#define NBUCK 64          // pixel-space buckets (p>>16), 256KB binpack slice each
#define NLIST 128         // 2 sides x 64 buckets
#define CAPG  139264      // per-list capacity: mean 131072, sigma~360, +big margin
#define WS_HIST_DST 0
#define WS_HIST_REF 3072
#define WS_TABLE    6144
#define WS_ACC      9216
#define WS_CURS     9728                        // uint[128]
#define WS_CTRL_BYTES 16384                     // zeroed each call
#define WS_SEL      16384                       // uchar[HH] (zeroed by prep)
#define WS_BPS      (16384 + (size_t)HH)        // uint[HH] binpack_src
#define WS_BPR      (WS_BPS + (size_t)HH * 4)   // uint[HH] binpack_ref
#define WS_LIST     (WS_BPR + (size_t)HH * 4)   // ushort[NLIST*CAPG]
#define WS_MAIN_BYTES (WS_LIST + (size_t)NLIST * CAPG * 2)

// ---------------- fallback (R3) ws layout ----------------
#define FB_CNT_DST  16384
#define FB_BINPACK  (16384 + (size_t)HH * 2)
#define FB_ZERO_BYTES (16384 + (size_t)HH * 2)

__device__ __forceinline__ int bin_of(float v) {
    int b = (int)floorf(v);
    return min(max(b, 0), BINS - 1);
}

// ============================================================
// MAIN PATH
// ============================================================

// Coalesced pass: packed 3-channel bin words for both sides + zero selected.
// mask==1 -> value in [127.5,255) -> bin in [127,254] (never 0), so
// word==0  <=>  mask==0.
__global__ __launch_bounds__(256) void prep_main(
    const float* __restrict__ mask_src, const float* __restrict__ mask_tar,
    const float* __restrict__ refimg, const float* __restrict__ tgtimg,
    unsigned int* __restrict__ bps, unsigned int* __restrict__ bpr,
    unsigned int* __restrict__ sel4)
{
    const int nq = HH / 4;
    const int stride = gridDim.x * 256;
    for (int q = blockIdx.x * 256 + threadIdx.x; q < nq; q += stride) {
        float4 ms4 = ((const float4*)mask_src)[q];
        float4 mt4 = ((const float4*)mask_tar)[q];
        const float ms[4] = { ms4.x, ms4.y, ms4.z, ms4.w };
        const float mt[4] = { mt4.x, mt4.y, mt4.z, mt4.w };
        unsigned int wsrc[4] = { 0u, 0u, 0u, 0u };
        unsigned int wref[4] = { 0u, 0u, 0u, 0u };
        #pragma unroll
        for (int c = 0; c < CH; ++c) {
            float4 r4 = ((const float4*)(refimg + (size_t)c * HH))[q];
            float4 t4 = ((const float4*)(tgtimg + (size_t)c * HH))[q];
            const float rr[4] = { r4.x, r4.y, r4.z, r4.w };
            const float tt[4] = { t4.x, t4.y, t4.z, t4.w };
            #pragma unroll
            for (int e = 0; e < 4; ++e) {
                float vs = (rr[e] * 0.5f + 0.5f) * 255.0f * ms[e];
                float vt = (tt[e] * 0.5f + 0.5f) * 255.0f * mt[e];
                wsrc[e] |= ((unsigned int)bin_of(vs)) << (8 * c);
                wref[e] |= ((unsigned int)bin_of(vt)) << (8 * c);
            }
        }
        uint4 o1 = { wsrc[0], wsrc[1], wsrc[2], wsrc[3] };
        uint4 o2 = { wref[0], wref[1], wref[2], wref[3] };
        ((uint4*)bps)[q] = o1;
        ((uint4*)bpr)[q] = o2;
        sel4[q] = 0u;
    }
}

// Bucket all sample positions by p>>16 via LDS staging.
#define P1_BLOCKS 512
#define P1_SPB (NIDX / P1_BLOCKS)   // 4096 samples/block
#define P1_CAP 128                  // per-list LDS capacity (mean fill 64)

__global__ __launch_bounds__(256) void partition_kernel(
    const int* __restrict__ idx0, const int* __restrict__ idx1,
    const int* __restrict__ idx2, const int* __restrict__ idx3,
    unsigned short* __restrict__ list_g, unsigned int* __restrict__ curs)
{
    __shared__ unsigned short stage[NLIST * P1_CAP];   // 32 KB
    __shared__ unsigned int lcnt[NLIST];
    __shared__ unsigned int lbase[NLIST];
    for (int i = threadIdx.x; i < NLIST; i += 256) lcnt[i] = 0u;
    __syncthreads();

    const int base_k = blockIdx.x * P1_SPB;
    for (int r = 0; r < P1_SPB / 256; ++r) {
        int k = base_k + r * 256 + threadIdx.x;
        int pd = idx0[k] * H + idx1[k];
        int pr = idx2[k] * H + idx3[k];
        {
            int l = pd >> 16;  // 0..63
            unsigned int pos = atomicAdd(&lcnt[l], 1u);
            if (pos < P1_CAP) stage[l * P1_CAP + pos] = (unsigned short)(pd & 0xFFFF);
            else {  // statistically ~impossible overflow slow path
                unsigned int g = atomicAdd(&curs[l], 1u);
                if (g < CAPG) list_g[(size_t)l * CAPG + g] = (unsigned short)(pd & 0xFFFF);
            }
        }
        {
            int l = 64 + (pr >> 16);
            unsigned int pos = atomicAdd(&lcnt[l], 1u);
            if (pos < P1_CAP) stage[l * P1_CAP + pos] = (unsigned short)(pr & 0xFFFF);
            else {
                unsigned int g = atomicAdd(&curs[l], 1u);
                if (g < CAPG) list_g[(size_t)l * CAPG + g] = (unsigned short)(pr & 0xFFFF);
            }
        }
    }
    __syncthreads();
    if (threadIdx.x < NLIST) {
        unsigned int n = min(lcnt[threadIdx.x], (unsigned int)P1_CAP);
        lbase[threadIdx.x] = atomicAdd(&curs[threadIdx.x], n);
    }
    __syncthreads();
    for (int b = 0; b < NLIST; ++b) {
        int n = (int)min(lcnt[b], (unsigned int)P1_CAP);
        unsigned int gb = lbase[b];
        for (int e = threadIdx.x; e < n; e += 256) {
            unsigned int gi = gb + e;
            if (gi < CAPG) list_g[(size_t)b * CAPG + gi] = stage[b * P1_CAP + e];
        }
    }
}

// XCD-localized gather: block b -> xcd b%8 -> buckets [8*xcd, 8*xcd+8).
// Random reads confined to ~0.6 MB per XCD per phase -> L2-resident.
__global__ __launch_bounds__(256) void gather_hist_kernel(
    const unsigned short* __restrict__ list_g, const unsigned int* __restrict__ curs,
    const unsigned int* __restrict__ bps, const unsigned int* __restrict__ bpr,
    unsigned char* __restrict__ selected,
    unsigned int* __restrict__ hist_dst, unsigned int* __restrict__ hist_ref)
{
    __shared__ unsigned int hd[CH * BINS];
    __shared__ unsigned int hr[CH * BINS];
    for (int i = threadIdx.x; i < CH * BINS; i += 256) { hd[i] = 0u; hr[i] = 0u; }
    __syncthreads();

    const int xcd = blockIdx.x & 7;
    const int j = blockIdx.x >> 3;   // 0..255 (grid 2048)
    unsigned int zc_d = 0, zc_r = 0;

    for (int phase = 0; phase < 8; ++phase) {
        const int bucket = xcd * 8 + phase;
        const unsigned int pbase = ((unsigned int)bucket) << 16;
        // dst side: histogram + selected mark
        {
            const int l = bucket;
            unsigned int n = min(curs[l], (unsigned int)CAPG);
            unsigned int chunk = (n + 255u) >> 8;
            unsigned int s = j * chunk;
            unsigned int e = min(s + chunk, n);
            for (unsigned int i = s + threadIdx.x; i < e; i += 256) {
                unsigned int p = pbase | (unsigned int)list_g[(size_t)l * CAPG + i];
                unsigned int w = bps[p];
                selected[p] = 1;
                if (w == 0u) ++zc_d;
                else {
                    atomicAdd(&hd[0 * BINS + (w & 0xFFu)], 1u);
                    atomicAdd(&hd[1 * BINS + ((w >> 8) & 0xFFu)], 1u);
                    atomicAdd(&hd[2 * BINS + ((w >> 16) & 0xFFu)], 1u);
                }
            }
        }
        // ref side
        {
            const int l = 64 + bucket;
            unsigned int n = min(curs[l], (unsigned int)CAPG);
            unsigned int chunk = (n + 255u) >> 8;
            unsigned int s = j * chunk;
            unsigned int e = min(s + chunk, n);
            for (unsigned int i = s + threadIdx.x; i < e; i += 256) {
                unsigned int p = pbase | (unsigned int)list_g[(size_t)l * CAPG + i];
                unsigned int w = bpr[p];
                if (w == 0u) ++zc_r;
                else {
                    atomicAdd(&hr[0 * BINS + (w & 0xFFu)], 1u);
                    atomicAdd(&hr[1 * BINS + ((w >> 8) & 0xFFu)], 1u);
                    atomicAdd(&hr[2 * BINS + ((w >> 16) & 0xFFu)], 1u);
                }
            }
        }
    }

    int zd = (int)zc_d, zr = (int)zc_r;
    #pragma unroll
    for (int off = 32; off; off >>= 1) { zd += __shfl_down(zd, off); zr += __shfl_down(zr, off); }
    if ((threadIdx.x & 63) == 0) {
        if (zd) {
            atomicAdd(&hd[0 * BINS], (unsigned int)zd);
            atomicAdd(&hd[1 * BINS], (unsigned int)zd);
            atomicAdd(&hd[2 * BINS], (unsigned int)zd);
        }
        if (zr) {
            atomicAdd(&hr[0 * BINS], (unsigned int)zr);
            atomicAdd(&hr[1 * BINS], (unsigned int)zr);
            atomicAdd(&hr[2 * BINS], (unsigned int)zr);
        }
    }

    __syncthreads();
    for (int i = threadIdx.x; i < CH * BINS; i += 256) {
        unsigned int v = hd[i];
        if (v) atomicAdd(&hist_dst[i], v);
        v = hr[i];
        if (v) atomicAdd(&hist_ref[i], v);
    }
}

// Table build: shuffle-scan cumsum (exact: integer-valued f32 < 2^24, any
// add order is bit-identical to the sequential reference) + binary search.
// The reference's "first j with cr[j] <= r <= cr[j+1]" over a non-decreasing
// cr equals: pos = first index in [1,255] with cr[pos] >= r; found iff
// cr[pos-1] <= r; table = found ? pos : i. IEEE comparisons identical.
__global__ __launch_bounds__(256) void table_kernel(
    const unsigned int* __restrict__ hist_dst,
    const unsigned int* __restrict__ hist_ref,
    int* __restrict__ table)
{
    __shared__ float cd[CH * BINS];
    __shared__ float cr[CH * BINS];
    __shared__ float wpart[4];
    const int i = threadIdx.x;        // 0..255
    const int lane = i & 63;
    const int wave = i >> 6;

    for (int a = 0; a < 6; ++a) {
        const unsigned int* h = (a < 3) ? (hist_dst + a * BINS) : (hist_ref + (a - 3) * BINS);
        float* out = (a < 3) ? (cd + a * BINS) : (cr + (a - 3) * BINS);
        float x = (float)h[i];
        #pragma unroll
        for (int off = 1; off < 64; off <<= 1) {
            float y = __shfl_up(x, off);
            if (lane >= off) x += y;
        }
        if (lane == 63) wpart[wave] = x;
        __syncthreads();
        float prefix = 0.0f;
        #pragma unroll
        for (int w = 0; w < 3; ++w) if (w < wave) prefix += wpart[w];
        x += prefix;
        float tot = wpart[0] + wpart[1] + wpart[2] + wpart[3];
        out[i] = x / tot;
        __syncthreads();   // protect wpart reuse + publish out[]
    }

    #pragma unroll
    for (int c = 0; c < CH; ++c) {
        int t;
        if (i == 0) t = 0;
        else if (i == BINS - 1) t = BINS - 1;
        else {
            float r = cd[c * BINS + i];
            int lo = 1, hi = BINS - 1;
            while (lo < hi) {
                int mid = (lo + hi) >> 1;
                if (cr[c * BINS + mid] < r) lo = mid + 1; else hi = mid;
            }
            t = (cr[c * BINS + lo - 1] <= r) ? lo : i;
        }
        table[c * BINS + i] = t;
    }
}

__global__ __launch_bounds__(256) void loss_sel_kernel(
    const float* __restrict__ input, const float* __restrict__ refimg,
    const float* __restrict__ mask_src, const unsigned char* __restrict__ selected,
    const int* __restrict__ table, double* __restrict__ acc)
{
    __shared__ int tab[CH * BINS];
    for (int i = threadIdx.x; i < CH * BINS; i += 256) tab[i] = table[i];
    __syncthreads();

    float lsum = 0.0f;
    const int nq = HH / 4;
    const int stride = gridDim.x * 256;
    for (int q = blockIdx.x * 256 + threadIdx.x; q < nq; q += stride) {
        float4 m4 = ((const float4*)mask_src)[q];
        uchar4 s4 = ((const uchar4*)selected)[q];
        const unsigned char ss[4] = { s4.x, s4.y, s4.z, s4.w };
        const float mm[4] = { m4.x, m4.y, m4.z, m4.w };
        #pragma unroll
        for (int c = 0; c < CH; ++c) {
            float4 a4 = ((const float4*)(input + (size_t)c * HH))[q];
            float4 r4 = ((const float4*)(refimg + (size_t)c * HH))[q];
            const float aa[4] = { a4.x, a4.y, a4.z, a4.w };
            const float rr[4] = { r4.x, r4.y, r4.z, r4.w };
            #pragma unroll
            for (int e = 0; e < 4; ++e) {
                float m = mm[e];
                float av = (aa[e] * 0.5f + 0.5f) * 255.0f * m;
                float rv = (rr[e] * 0.5f + 0.5f) * 255.0f * m;
                float tv = (float)tab[c * BINS + bin_of(rv)];
                float mv = m * (ss[e] ? tv : rv);
                lsum += fabsf(av - mv);
            }
        }
    }

    double d = (double)lsum;
    #pragma unroll
    for (int off = 32; off; off >>= 1) d += __shfl_down(d, off);
    __shared__ double wsum[4];
    int wid = threadIdx.x >> 6;
    int lane = threadIdx.x & 63;
    if (lane == 0) wsum[wid] = d;
    __syncthreads();
    if (threadIdx.x == 0) {
        double t = wsum[0] + wsum[1] + wsum[2] + wsum[3];
        atomicAdd(acc, t);
    }
}

__global__ void finalize_kernel(const double* __restrict__ acc, float* __restrict__ out)
{
    if (threadIdx.x == 0 && blockIdx.x == 0) {
        out[0] = (float)(acc[0] / (double)(CH * (double)HH));
    }
}

// ============================================================
// FALLBACK PATH (proven R3 pipeline) — used if ws_size too small
// ============================================================

__device__ __forceinline__ void cnt_inc(unsigned int* cnt, int p) {
    atomicAdd(&cnt[p >> 1], (p & 1) ? 0x10000u : 1u);
}

__global__ __launch_bounds__(256) void fb_prep_kernel(
    const float* __restrict__ mask_tar, const float* __restrict__ tgtimg,
    unsigned int* __restrict__ binpack)
{
    const int nq = HH / 4;
    const int stride = gridDim.x * 256;
    for (int q = blockIdx.x * 256 + threadIdx.x; q < nq; q += stride) {
        float4 m4 = ((const float4*)mask_tar)[q];
        const float mm[4] = { m4.x, m4.y, m4.z, m4.w };
        unsigned int w[4] = { 0u, 0u, 0u, 0u };
        #pragma unroll
        for (int c = 0; c < CH; ++c) {
            float4 t4 = ((const float4*)(tgtimg + (size_t)c * HH))[q];
            const float tt[4] = { t4.x, t4.y, t4.z, t4.w };
            #pragma unroll
            for (int e = 0; e < 4; ++e) {
                float v = (tt[e] * 0.5f + 0.5f) * 255.0f * mm[e];
                w[e] |= ((unsigned int)bin_of(v)) << (8 * c);
            }
        }
        uint4 out = { w[0], w[1], w[2], w[3] };
        ((uint4*)binpack)[q] = out;
    }
}

__global__ __launch_bounds__(256) void fb_scatter_kernel(
    const int4* __restrict__ idx0, const int4* __restrict__ idx1,
    const int4* __restrict__ idx2, const int4* __restrict__ idx3,
    const unsigned int* __restrict__ binpack,
    unsigned int* __restrict__ cnt_dst, unsigned int* __restrict__ hist_ref)
{
    __shared__ unsigned int hr[CH * BINS];
    for (int i = threadIdx.x; i < CH * BINS; i += 256) hr[i] = 0u;
    __syncthreads();

    unsigned int zc = 0;
    const int n4 = NIDX / 4;
    const int stride = gridDim.x * 256;
    for (int k = blockIdx.x * 256 + threadIdx.x; k < n4; k += stride) {
        int4 a = idx0[k], b = idx1[k], c = idx2[k], d = idx3[k];
        int p0 = c.x * H + d.x, p1 = c.y * H + d.y;
        int p2 = c.z * H + d.z, p3 = c.w * H + d.w;
        unsigned int w0 = binpack[p0], w1 = binpack[p1];
        unsigned int w2 = binpack[p2], w3 = binpack[p3];

        cnt_inc(cnt_dst, a.x * H + b.x);
        cnt_inc(cnt_dst, a.y * H + b.y);
        cnt_inc(cnt_dst, a.z * H + b.z);
        cnt_inc(cnt_dst, a.w * H + b.w);

        const unsigned int ws2[4] = { w0, w1, w2, w3 };
        #pragma unroll
        for (int e = 0; e < 4; ++e) {
            unsigned int w = ws2[e];
            if (w == 0u) ++zc;
            else {
                atomicAdd(&hr[0 * BINS + (w & 0xFFu)], 1u);
                atomicAdd(&hr[1 * BINS + ((w >> 8) & 0xFFu)], 1u);
                atomicAdd(&hr[2 * BINS + ((w >> 16) & 0xFFu)], 1u);
            }
        }
    }

    int z = (int)zc;
    #pragma unroll
    for (int off = 32; off; off >>= 1) z += __shfl_down(z, off);
    if ((threadIdx.x & 63) == 0 && z) {
        atomicAdd(&hr[0 * BINS], (unsigned int)z);
        atomicAdd(&hr[1 * BINS], (unsigned int)z);
        atomicAdd(&hr[2 * BINS], (unsigned int)z);
    }

    __syncthreads();
    for (int i = threadIdx.x; i < CH * BINS; i += 256) {
        unsigned int v = hr[i];
        if (v) atomicAdd(&hist_ref[i], v);
    }
}

__global__ __launch_bounds__(256) void fb_sweep_kernel(
    const float* __restrict__ mask_src, const float* __restrict__ refimg,
    const unsigned int* __restrict__ cnt_dst,
    unsigned int* __restrict__ hist_dst)
{
    __shared__ unsigned int hd[CH * BINS];
    for (int i = threadIdx.x; i < CH * BINS; i += 256) hd[i] = 0u;
    __syncthreads();

    unsigned int zc = 0;
    const int nq = HH / 4;
    const int stride = gridDim.x * 256;
    for (int q = blockIdx.x * 256 + threadIdx.x; q < nq; q += stride) {
        uint2 wd = ((const uint2*)cnt_dst)[q];
        unsigned int cdc[4] = { wd.x & 0xFFFFu, wd.x >> 16, wd.y & 0xFFFFu, wd.y >> 16 };
        float4 ms4 = ((const float4*)mask_src)[q];
        const float ms[4] = { ms4.x, ms4.y, ms4.z, ms4.w };

        float rv[CH][4];
        #pragma unroll
        for (int c = 0; c < CH; ++c) {
            float4 r4 = ((const float4*)(refimg + (size_t)c * HH))[q];
            rv[c][0] = r4.x; rv[c][1] = r4.y; rv[c][2] = r4.z; rv[c][3] = r4.w;
        }
        #pragma unroll
        for (int e = 0; e < 4; ++e) {
            if (cdc[e]) {
                if (ms[e] == 0.0f) zc += cdc[e];
                else {
                    #pragma unroll
                    for (int c = 0; c < CH; ++c) {
                        float v = (rv[c][e] * 0.5f + 0.5f) * 255.0f;
                        atomicAdd(&hd[c * BINS + bin_of(v)], cdc[e]);
                    }
                }
            }
        }
    }

    int z = (int)zc;
    #pragma unroll
    for (int off = 32; off; off >>= 1) z += __shfl_down(z, off);
    if ((threadIdx.x & 63) == 0 && z) {
        atomicAdd(&hd[0 * BINS], (unsigned int)z);
        atomicAdd(&hd[1 * BINS], (unsigned int)z);
        atomicAdd(&hd[2 * BINS], (unsigned int)z);
    }

    __syncthreads();
    for (int i = threadIdx.x; i < CH * BINS; i += 256) {
        unsigned int v = hd[i];
        if (v) atomicAdd(&hist_dst[i], v);
    }
}

__global__ __launch_bounds__(256) void fb_loss_kernel(
    const float* __restrict__ input, const float* __restrict__ refimg,
    const float* __restrict__ mask_src, const unsigned int* __restrict__ cnt_dst,
    const int* __restrict__ table, double* __restrict__ acc)
{
    __shared__ int tab[CH * BINS];
    for (int i = threadIdx.x; i < CH * BINS; i += 256) tab[i] = table[i];
    __syncthreads();

    float lsum = 0.0f;
    const int nq = HH / 4;
    const int stride = gridDim.x * 256;
    for (int q = blockIdx.x * 256 + threadIdx.x; q < nq; q += stride) {
        float4 m4 = ((const float4*)mask_src)[q];
        uint2 w = ((const uint2*)cnt_dst)[q];
        const unsigned int sel[4] = { w.x & 0xFFFFu, w.x >> 16, w.y & 0xFFFFu, w.y >> 16 };
        const float mm[4] = { m4.x, m4.y, m4.z, m4.w };
        #pragma unroll
        for (int c = 0; c < CH; ++c) {
            float4 a4 = ((const float4*)(input + (size_t)c * HH))[q];
            float4 r4 = ((const float4*)(refimg + (size_t)c * HH))[q];
            const float aa[4] = { a4.x, a4.y, a4.z, a4.w };
            const float rr[4] = { r4.x, r4.y, r4.z, r4.w };
            #pragma unroll
            for (int e = 0; e < 4; ++e) {
                float m = mm[e];
                float av = (aa[e] * 0.5f + 0.5f) * 255.0f * m;
                float rv = (rr[e] * 0.5f + 0.5f) * 255.0f * m;
                float tv = (float)tab[c * BINS + bin_of(rv)];
                float mv = m * (sel[e] ? tv : rv);
                lsum += fabsf(av - mv);
            }
        }
    }

    double d = (double)lsum;
    #pragma unroll
    for (int off = 32; off; off >>= 1) d += __shfl_down(d, off);
    __shared__ double wsum[4];
    int wid = threadIdx.x >> 6;
    int lane = threadIdx.x & 63;
    if (lane == 0) wsum[wid] = d;
    __syncthreads();
    if (threadIdx.x == 0) {
        double t = wsum[0] + wsum[1] + wsum[2] + wsum[3];
        atomicAdd(acc, t);
    }
}

// ============================================================

extern "C" void kernel_launch(void* const* d_in, const int* in_sizes, int n_in,
                              void* d_out, int out_size, void* d_ws, size_t ws_size,
                              hipStream_t stream)
{
    const float* input    = (const float*)d_in[0];
    const float* target   = (const float*)d_in[1];
    const float* mask_src = (const float*)d_in[2];
    const float* mask_tar = (const float*)d_in[3];
    const int*   idx0     = (const int*)d_in[4];
    const int*   idx1     = (const int*)d_in[5];
    const int*   idx2     = (const int*)d_in[6];
    const int*   idx3     = (const int*)d_in[7];
    const float* refimg   = (const float*)d_in[8];

    char* ws = (char*)d_ws;
    unsigned int* hist_dst = (unsigned int*)(ws + WS_HIST_DST);
    unsigned int* hist_ref = (unsigned int*)(ws + WS_HIST_REF);
    int*          table    = (int*)(ws + WS_TABLE);
    double*       acc      = (double*)(ws + WS_ACC);

    if (ws_size >= WS_MAIN_BYTES) {
        unsigned int*   curs     = (unsigned int*)(ws + WS_CURS);
        unsigned char*  selected = (unsigned char*)(ws + WS_SEL);
        unsigned int*   bps      = (unsigned int*)(ws + WS_BPS);
        unsigned int*   bpr      = (unsigned int*)(ws + WS_BPR);
        unsigned short* list_g   = (unsigned short*)(ws + WS_LIST);

        hipMemsetAsync(d_ws, 0, WS_CTRL_BYTES, stream);
        prep_main<<<2048, 256, 0, stream>>>(mask_src, mask_tar, refimg, target,
                                            bps, bpr, (unsigned int*)selected);
        partition_kernel<<<P1_BLOCKS, 256, 0, stream>>>(idx0, idx1, idx2, idx3,
                                                        list_g, curs);
        gather_hist_kernel<<<2048, 256, 0, stream>>>(list_g, curs, bps, bpr,
                                                     selected, hist_dst, hist_ref);
        table_kernel<<<1, 256, 0, stream>>>(hist_dst, hist_ref, table);
        loss_sel_kernel<<<2048, 256, 0, stream>>>(input, refimg, mask_src,
                                                  selected, table, acc);
        finalize_kernel<<<1, 64, 0, stream>>>(acc, (float*)d_out);
    } else {
        unsigned int* cnt_dst = (unsigned int*)(ws + FB_CNT_DST);
        unsigned int* binpack = (unsigned int*)(ws + FB_BINPACK);

        hipMemsetAsync(d_ws, 0, FB_ZERO_BYTES, stream);
        fb_prep_kernel<<<2048, 256, 0, stream>>>(mask_tar, target, binpack);
        fb_scatter_kernel<<<2048, 256, 0, stream>>>((const int4*)idx0, (const int4*)idx1,
                                                    (const int4*)idx2, (const int4*)idx3,
                                                    binpack, cnt_dst, hist_ref);
        fb_sweep_kernel<<<1024, 256, 0, stream>>>(mask_src, refimg, cnt_dst, hist_dst);
        table_kernel<<<1, 256, 0, stream>>>(hist_dst, hist_ref, table);
        fb_loss_kernel<<<2048, 256, 0, stream>>>(input, refimg, mask_src, cnt_dst,
                                                 table, acc);
        finalize_kernel<<<1, 64, 0, stream>>>(acc, (float*)d_out);
    }
}